// Round 6
// baseline (77.736 us; speedup 1.0000x reference)
//
#include <hip/hip_runtime.h>
#include <math.h>

#define BB 2
#define TSS 12
#define NN 5000
#define EE 80000
#define NHEAD 4
#define NOUT 16
#define NEMB 64
#define NCCH 64
#define KW 3
#define NHOR 12
#define NBT (BB*TSS)     // 24
#define NEG 0.2f
#define CAP 64           // per-node bucket capacity; Poisson(16) tail ~1e-18
#define BLK 512
#define NPB 8            // nodes per block
#define NGRID (NN/NPB)   // 625

__device__ __forceinline__ float lrelu(float v) { return v >= 0.f ? v : NEG * v; }

// cooperative per-block precompute of fused small weights into LDS
__device__ __forceinline__ void wtask(int tsk,
    const float* __restrict__ Wg, const float* __restrict__ a_src,
    const float* __restrict__ a_dst, const float* __restrict__ bg,
    const float* __restrict__ Wc,
    float* __restrict__ wcwS, float* __restrict__ cbS, float* __restrict__ csS)
{
    if (tsk < 768) {                       // WcW[o][hd][k]
        int o = tsk / 12, r = tsk % 12, hd = r / 3, k = r % 3;
        float s = 0.f;
#pragma unroll
        for (int d = 0; d < NOUT; ++d)
            s += Wg[hd * NOUT + d] * Wc[(o * NEMB + hd * NOUT + d) * KW + k];
        wcwS[tsk] = s;
    } else if (tsk < 960) {                // cb[o][k]
        int q = tsk - 768; int o = q / 3, k = q % 3;
        float s = 0.f;
#pragma unroll
        for (int c = 0; c < NEMB; ++c)
            s += bg[c] * Wc[(o * NEMB + c) * KW + k];
        cbS[q] = s;
    } else if (tsk < 968) {                // cs[0..3], cd[4..7]
        int i = tsk - 960; int h = i & 3;
        const float* av = (i < 4) ? a_src : a_dst;
        float s = 0.f;
#pragma unroll
        for (int d = 0; d < NOUT; ++d) s += Wg[h * NOUT + d] * av[h * NOUT + d];
        csS[i] = s;
    }
}

__global__ __launch_bounds__(BLK, 4) void k_all(
    const float* __restrict__ x, const int* __restrict__ ei,
    const float* __restrict__ Wg, const float* __restrict__ a_src,
    const float* __restrict__ a_dst, const float* __restrict__ bg,
    const float* __restrict__ Wc, const float* __restrict__ bc,
    const float* __restrict__ Wh, const float* __restrict__ bh,
    float* __restrict__ out)
{
    __shared__ float wcwS[768];
    __shared__ float cbS[192];
    __shared__ float csS[8];
    __shared__ int   lcnt[NPB];
    __shared__ int   lbkt[NPB][CAP];
    __shared__ float sS[NPB][NBT][NHEAD];
    __shared__ float sz[NPB][BB][NCCH];

    int tid = threadIdx.x;
    int node0 = blockIdx.x * NPB;

    if (tid < NPB) lcnt[tid] = 0;
    wtask(tid,        Wg, a_src, a_dst, bg, Wc, wcwS, cbS, csS);
    wtask(tid + BLK,  Wg, a_src, a_dst, bg, Wc, wcwS, cbS, csS);
    __syncthreads();

    // ---- edge scan: find edges whose dst is in [node0, node0+8) ----
    const int4* dst4 = (const int4*)(ei + EE);
    for (int it = 0; it < 39; ++it) {                  // 39*512*4 = 79872
        int vec = it * BLK + tid;
        int4 d4 = dst4[vec];
        int ebase = vec * 4;
        int dv[4] = { d4.x, d4.y, d4.z, d4.w };
#pragma unroll
        for (int j = 0; j < 4; ++j) {
            unsigned r = (unsigned)(dv[j] - node0);
            if (r < (unsigned)NPB) {
                int pos = atomicAdd(&lcnt[r], 1);
                if (pos < CAP) lbkt[r][pos] = ei[ebase + j];
            }
        }
    }
    if (tid < EE - 79872) {                            // tail 128 edges
        int e = 79872 + tid;
        unsigned r = (unsigned)(ei[EE + e] - node0);
        if (r < (unsigned)NPB) {
            int pos = atomicAdd(&lcnt[r], 1);
            if (pos < CAP) lbkt[r][pos] = ei[e];
        }
    }
    __syncthreads();

    // ---- segment softmax-aggregate: 8 lanes per (node, bt) ----
    int u = tid >> 6, ul = tid & 63, g = ul >> 3, gl = ul & 7;
    int node = node0 + u;
    int cnt = lcnt[u]; if (cnt > CAP) cnt = CAP;
    float c0 = csS[0], c1 = csS[1], c2 = csS[2], c3 = csS[3];
    float q0 = csS[4], q1 = csS[5], q2 = csS[6], q3 = csS[7];

    int idxr[8];
#pragma unroll
    for (int i = 0; i < 8; ++i) {
        int e = gl + (i << 3);
        idxr[i] = (e < cnt) ? lbkt[u][e] : 0;
    }

    for (int it = 0; it < 3; ++it) {
        int bt = g + (it << 3);
        const float* xb = x + bt * NN;
        float xd = xb[node];
        float d0 = q0*xd, d1 = q1*xd, d2 = q2*xd, d3 = q3*xd;

        float xsr[8];
        float mx = -INFINITY, mn = INFINITY;
#pragma unroll
        for (int i = 0; i < 8; ++i) {
            int e = gl + (i << 3);
            if (e < cnt) {
                float v = xb[idxr[i]];
                xsr[i] = v;
                mx = fmaxf(mx, v); mn = fminf(mn, v);
            }
        }
#pragma unroll
        for (int m = 1; m < 8; m <<= 1) {
            mx = fmaxf(mx, __shfl_xor(mx, m));
            mn = fminf(mn, __shfl_xor(mn, m));
        }
        // exact per-head max (leaky_relu(affine) monotone in xs)
        float m0 = lrelu((c0 >= 0.f ? c0*mx : c0*mn) + d0);
        float m1 = lrelu((c1 >= 0.f ? c1*mx : c1*mn) + d1);
        float m2 = lrelu((c2 >= 0.f ? c2*mx : c2*mn) + d2);
        float m3 = lrelu((c3 >= 0.f ? c3*mx : c3*mn) + d3);

        float a0=0.f,a1=0.f,a2=0.f,a3=0.f, b0=0.f,b1=0.f,b2=0.f,b3=0.f;
#pragma unroll
        for (int i = 0; i < 8; ++i) {
            int e = gl + (i << 3);
            if (e < cnt) {
                float xs = xsr[i];
                float w0 = __expf(lrelu(c0*xs + d0) - m0); a0 += w0; b0 += w0*xs;
                float w1 = __expf(lrelu(c1*xs + d1) - m1); a1 += w1; b1 += w1*xs;
                float w2 = __expf(lrelu(c2*xs + d2) - m2); a2 += w2; b2 += w2*xs;
                float w3 = __expf(lrelu(c3*xs + d3) - m3); a3 += w3; b3 += w3*xs;
            }
        }
#pragma unroll
        for (int m = 1; m < 8; m <<= 1) {
            a0 += __shfl_xor(a0, m); a1 += __shfl_xor(a1, m);
            a2 += __shfl_xor(a2, m); a3 += __shfl_xor(a3, m);
            b0 += __shfl_xor(b0, m); b1 += __shfl_xor(b1, m);
            b2 += __shfl_xor(b2, m); b3 += __shfl_xor(b3, m);
        }
        if (gl < 4) {
            float av = gl==0 ? a0 : gl==1 ? a1 : gl==2 ? a2 : a3;
            float bv = gl==0 ? b0 : gl==1 ? b1 : gl==2 ? b2 : b3;
            sS[u][bt][gl] = bv / (av + 1e-16f);
        }
    }
    __syncthreads();

    // ---- temporal conv + relu + mean, per output channel o = ul ----
    int o = ul;
    float wcw[NHEAD][KW];
#pragma unroll
    for (int hd = 0; hd < NHEAD; ++hd)
#pragma unroll
        for (int k = 0; k < KW; ++k)
            wcw[hd][k] = wcwS[o * (NHEAD * KW) + hd * KW + k];
    float cbk[KW];
#pragma unroll
    for (int k = 0; k < KW; ++k) cbk[k] = cbS[o * KW + k];
    float bco = bc[o];
#pragma unroll
    for (int b = 0; b < BB; ++b) {
        float acc = 0.f;
#pragma unroll
        for (int t = 0; t < TSS; ++t) {
            float zt = bco;
#pragma unroll
            for (int k = 0; k < KW; ++k) {
                int tau = t + k - 1;
                if (tau >= 0 && tau < TSS) {
                    zt += cbk[k];
#pragma unroll
                    for (int hd = 0; hd < NHEAD; ++hd)
                        zt += sS[u][b * TSS + tau][hd] * wcw[hd][k];
                }
            }
            acc += fmaxf(zt, 0.f);
        }
        sz[u][b][o] = acc * (1.f / 12.f);
    }
    __syncthreads();

    // ---- head linear + output ----
    if (o < NHOR) {
#pragma unroll
        for (int b = 0; b < BB; ++b) {
            float y = bh[o];
#pragma unroll
            for (int c = 0; c < NCCH; ++c) y += sz[u][b][c] * Wh[o * NCCH + c];
            out[(b * NHOR + o) * NN + node] = y;
        }
    }
}

extern "C" void kernel_launch(void* const* d_in, const int* in_sizes, int n_in,
                              void* d_out, int out_size, void* d_ws, size_t ws_size,
                              hipStream_t stream) {
    const float* x     = (const float*)d_in[0];
    const int*   ei    = (const int*)d_in[1];
    const float* Wg    = (const float*)d_in[2];
    const float* a_src = (const float*)d_in[3];
    const float* a_dst = (const float*)d_in[4];
    const float* bg    = (const float*)d_in[5];
    const float* Wc    = (const float*)d_in[6];
    const float* bc    = (const float*)d_in[7];
    const float* Wh    = (const float*)d_in[8];
    const float* bh    = (const float*)d_in[9];
    float* out = (float*)d_out;

    hipLaunchKernelGGL(k_all, dim3(NGRID), dim3(BLK), 0, stream,
                       x, ei, Wg, a_src, a_dst, bg, Wc, bc, Wh, bh, out);
}